// Round 10
// baseline (88.167 us; speedup 1.0000x reference)
//
#include <hip/hip_runtime.h>

#define HH    1024
#define WW    1024
#define KS    15
#define PAD   7
#define CELL  256
#define BX    64            // x-width per block (4 waves x 16)
#define STRIP 128           // output rows per block
#define TROWS (STRIP + 2*PAD)   // 142
#define TCOLS 80            // staged halves per row (160B rows)
#define NJP   (STRIP / 16)  // 8 row-patches
#define NGRP  (TROWS * 20)  // 2840 float4 groups
#define NFULL 11            // full staging slices (2816), tail = 24
#define AWS_CELL_BYTES (KS * 1024)   // 15 fragments x 1KB

typedef _Float16     f16x8 __attribute__((ext_vector_type(8)));
typedef _Float16     f16x4 __attribute__((ext_vector_type(4)));
typedef float        f32x4 __attribute__((ext_vector_type(4)));
typedef unsigned int u32x4 __attribute__((ext_vector_type(4)));

// ---- prep: materialize normalized Toeplitz A fragments per cell into d_ws ----
__global__ __launch_bounds__(256) void pb_prep_kernel(
    const float* __restrict__ kern, unsigned int* __restrict__ aws)
{
    const int cell = blockIdx.x;           // cj*4+ci
    const int tid  = threadIdx.x;
    const int lane = tid & 63;
    const float* kp = kern + cell * (KS * KS);

    float s = 0.f;
    #pragma unroll
    for (int i = 0; i < 4; ++i) {
        int t = lane + 64 * i;
        s += (t < KS * KS) ? kp[t] : 0.f;
    }
    #pragma unroll
    for (int m = 1; m < 64; m <<= 1) s += __shfl_xor(s, m, 64);
    const float inv = 1.0f / (s + 1e-12f);

    const int i  = tid >> 4;               // x-position (A row)
    const int k2 = tid & 15;               // half-pair index
    unsigned int* wp = aws + cell * (AWS_CELL_BYTES / 4) + tid;

    for (int dy = 0; dy < KS; ++dy) {
        float v0 = 0.f, v1 = 0.f;
        int dx0 = 2 * k2 - i - 1;          // A[i][k] = kh[k-i-1]
        int dx1 = dx0 + 1;
        if (dx0 >= 0 && dx0 < KS) v0 = kp[dy * KS + dx0] * inv;
        if (dx1 >= 0 && dx1 < KS) v1 = kp[dy * KS + dx1] * inv;
        f16x4 h; h[0] = (_Float16)v0; h[1] = (_Float16)v1; h[2] = 0; h[3] = 0;
        unsigned long long u = __builtin_bit_cast(unsigned long long, h);
        wp[dy * 256] = (unsigned int)u;
    }
}

// ---- main ----
// Phase order is the point (R10): (1) issue ALL staging loads into vbuf[11]
// (deep vmem batch, one HBM latency), (2) issue af loads (L2-hot),
// (3) cvt+ds_write staged data, (4) barrier, (5) MFMA loop.
// vbuf (44 VGPR) and af (60 regs) are live in DIFFERENT phases -> allocator
// time-shares; cap 102 regs (5 waves/SIMD) via __launch_bounds__(256,5).
// R8 loaded af first -> only ~2-3 staging loads in flight -> latency-bound.
__global__ __launch_bounds__(256, 5) void pb_mfma_kernel(
    const float* __restrict__ x,
    const unsigned int* __restrict__ aws,
    float* __restrict__ out)
{
    __shared__ __align__(16) _Float16 s_tile[TROWS * TCOLS];   // 22720 B

    const int tid  = threadIdx.x;
    const int lane = tid & 63;
    const int w    = tid >> 6;           // wave id: x sub-block
    const int g    = lane >> 4;          // k-group 0..3
    const int cc   = lane & 15;          // A-row / B-col index

    const int bx0   = blockIdx.x * BX;
    const int ci    = blockIdx.x >> 2;   // cell col
    const int strip = blockIdx.y & 1;
    const int cj    = blockIdx.y >> 1;   // cell row
    const int bc    = blockIdx.z;        // plane (b*c)

    const int cellx0 = ci * CELL;
    const int celly0 = cj * CELL, celly1 = celly0 + CELL - 1;
    const int sy0    = celly0 + strip * STRIP;

    const float* plane = x + (size_t)bc * HH * WW;

    // ---- phase 1: issue all staging loads (clamped-aligned float4) ----
    auto group_addr = [&](int idx) -> const float* {
        int row  = idx / 20;
        int c4   = idx - row * 20;
        int gy   = min(max(sy0 - PAD + row, celly0), celly1);
        int gx0  = bx0 - 8 + 4 * c4;
        int gx0c = min(max(gx0, cellx0), cellx0 + CELL - 4);
        return plane + (size_t)gy * WW + gx0c;
    };

    float4 vbuf[NFULL];
    #pragma unroll
    for (int i = 0; i < NFULL; ++i)
        vbuf[i] = *(const float4*)group_addr(tid + 256 * i);
    const bool has_tail = tid < (NGRP - 256 * NFULL);
    float4 vtail = {0.f, 0.f, 0.f, 0.f};
    if (has_tail)
        vtail = *(const float4*)group_addr(256 * NFULL + tid);

    // ---- phase 2: af loads (independent, L2-hot, pipelined behind staging) ----
    const u32x4* ap = (const u32x4*)(aws + (cj * 4 + ci) * (AWS_CELL_BYTES / 4))
                      + cc * 4 + g;
    u32x4 af[KS];
    #pragma unroll
    for (int dy = 0; dy < KS; ++dy) af[dy] = ap[dy * 64];

    // ---- phase 3: convert + ds_write as vmcnt drains ----
    auto write_group = [&](int idx, float4 v) {
        int row = idx / 20;
        int c4  = idx - row * 20;
        int gx0 = bx0 - 8 + 4 * c4;
        bool lo = gx0 <  cellx0;
        bool hi = gx0 >  cellx0 + CELL - 4;
        float e0 = hi ? v.w : v.x;
        float e1 = lo ? v.x : (hi ? v.w : v.y);
        float e2 = lo ? v.x : (hi ? v.w : v.z);
        float e3 = lo ? v.x : v.w;
        f16x4 h;
        h[0] = (_Float16)e0; h[1] = (_Float16)e1;
        h[2] = (_Float16)e2; h[3] = (_Float16)e3;
        *(f16x4*)(s_tile + row * TCOLS + 4 * c4) = h;
    };
    #pragma unroll
    for (int i = 0; i < NFULL; ++i)
        write_group(tid + 256 * i, vbuf[i]);
    if (has_tail)
        write_group(256 * NFULL + tid, vtail);

    // pin af: loaded once, resident through the jp loop
    #pragma unroll
    for (int dy = 0; dy < KS; ++dy) asm volatile("" : "+v"(af[dy]));

    __syncthreads();

    // ---- phase 5: 8 patches x 15 dy ----
    const _Float16* bbase = s_tile + cc * TCOLS + w * 16 + g * 8;
    float* oplane = out + (size_t)bc * HH * WW;

    #pragma unroll
    for (int jp = 0; jp < NJP; ++jp) {
        f32x4 acc0 = {0.f, 0.f, 0.f, 0.f};
        f32x4 acc1 = {0.f, 0.f, 0.f, 0.f};
        #pragma unroll
        for (int dy = 0; dy < KS; ++dy) {
            f16x8 b = *(const f16x8*)(bbase + (16 * jp + dy) * TCOLS);
            if (dy & 1)
                acc1 = __builtin_amdgcn_mfma_f32_16x16x32_f16(
                           __builtin_bit_cast(f16x8, af[dy]), b, acc1, 0, 0, 0);
            else
                acc0 = __builtin_amdgcn_mfma_f32_16x16x32_f16(
                           __builtin_bit_cast(f16x8, af[dy]), b, acc0, 0, 0, 0);
        }
        f32x4 r = acc0 + acc1;
        // D: col=lane&15 (image row), row=4*(lane>>4)+e (x position)
        float* op = oplane + (size_t)(sy0 + 16 * jp + cc) * WW + bx0 + 16 * w + 4 * g;
        *(f32x4*)op = r;
    }
}

extern "C" void kernel_launch(void* const* d_in, const int* in_sizes, int n_in,
                              void* d_out, int out_size, void* d_ws, size_t ws_size,
                              hipStream_t stream) {
    (void)in_sizes; (void)n_in; (void)ws_size; (void)out_size;
    const float* x    = (const float*)d_in[0];
    const float* kern = (const float*)d_in[1];
    float* out        = (float*)d_out;
    unsigned int* aws = (unsigned int*)d_ws;   // 16 cells x 15 KiB = 240 KiB

    pb_prep_kernel<<<16, 256, 0, stream>>>(kern, aws);
    dim3 grid(WW / BX, 8, 8 * 3);   // 16 x-strips, 8 y-strips, 24 planes
    pb_mfma_kernel<<<grid, 256, 0, stream>>>(x, aws, out);
}

// Round 11
// 57.902 us; speedup vs baseline: 1.5227x; 1.5227x over previous
//
#include <hip/hip_runtime.h>

#define HH    1024
#define WW    1024
#define KS    15
#define PAD   7
#define CELL  256
#define BX    64            // x-width per block (4 waves x 16)
#define STRIP 128           // output rows per block
#define TROWS (STRIP + 2*PAD)   // 142
#define TCOLS 80            // staged halves per row (160B rows)
#define NJP   (STRIP / 16)  // 8 row-patches
#define NGRP  (TROWS * 20)  // 2840 float4 groups
#define CGRP  320           // groups per 16-row chunk
#define NCHUNK 9            // ceil(142/16): last chunk 14 rows (280 groups)
#define AWS_CELL_BYTES (KS * 1024)   // 15 fragments x 1KB

typedef _Float16     f16x8 __attribute__((ext_vector_type(8)));
typedef _Float16     f16x4 __attribute__((ext_vector_type(4)));
typedef float        f32x4 __attribute__((ext_vector_type(4)));
typedef unsigned int u32x4 __attribute__((ext_vector_type(4)));

// ---- prep: materialize normalized Toeplitz A fragments per cell into d_ws ----
__global__ __launch_bounds__(256) void pb_prep_kernel(
    const float* __restrict__ kern, unsigned int* __restrict__ aws)
{
    const int cell = blockIdx.x;           // cj*4+ci
    const int tid  = threadIdx.x;
    const int lane = tid & 63;
    const float* kp = kern + cell * (KS * KS);

    float s = 0.f;
    #pragma unroll
    for (int i = 0; i < 4; ++i) {
        int t = lane + 64 * i;
        s += (t < KS * KS) ? kp[t] : 0.f;
    }
    #pragma unroll
    for (int m = 1; m < 64; m <<= 1) s += __shfl_xor(s, m, 64);
    const float inv = 1.0f / (s + 1e-12f);

    const int i  = tid >> 4;               // x-position (A row)
    const int k2 = tid & 15;               // half-pair index
    unsigned int* wp = aws + cell * (AWS_CELL_BYTES / 4) + tid;

    for (int dy = 0; dy < KS; ++dy) {
        float v0 = 0.f, v1 = 0.f;
        int dx0 = 2 * k2 - i - 1;          // A[i][k] = kh[k-i-1]
        int dx1 = dx0 + 1;
        if (dx0 >= 0 && dx0 < KS) v0 = kp[dy * KS + dx0] * inv;
        if (dx1 >= 0 && dx1 < KS) v1 = kp[dy * KS + dx1] * inv;
        f16x4 h; h[0] = (_Float16)v0; h[1] = (_Float16)v1; h[2] = 0; h[3] = 0;
        unsigned long long u = __builtin_bit_cast(unsigned long long, h);
        wp[dy * 256] = (unsigned int)u;
    }
}

// ---- main: R8 structure + chunked software-pipelined staging (T14) ----
// af[15] loaded once (coalesced, L2-hot) and pinned — R8-proven.
// Staging split into 16-row chunks (2 float4/thread in flight, 8 VGPRs);
// chunk jp+2's loads are issued BEFORE patch jp's MFMA work and written to
// LDS after it, so HBM latency hides under compute. R10's 48-reg batch
// spilled (WRITE 196 MB); this caps in-flight staging state at 2 loads.
__global__ __launch_bounds__(256, 4) void pb_mfma_kernel(
    const float* __restrict__ x,
    const unsigned int* __restrict__ aws,
    float* __restrict__ out)
{
    __shared__ __align__(16) _Float16 s_tile[TROWS * TCOLS];   // 22720 B

    const int tid  = threadIdx.x;
    const int lane = tid & 63;
    const int w    = tid >> 6;           // wave id: x sub-block
    const int g    = lane >> 4;          // k-group 0..3
    const int cc   = lane & 15;          // A-row / B-col index

    const int bx0   = blockIdx.x * BX;
    const int ci    = blockIdx.x >> 2;   // cell col
    const int strip = blockIdx.y & 1;
    const int cj    = blockIdx.y >> 1;   // cell row
    const int bc    = blockIdx.z;        // plane (b*c)

    const int cellx0 = ci * CELL;
    const int celly0 = cj * CELL, celly1 = celly0 + CELL - 1;
    const int sy0    = celly0 + strip * STRIP;

    const float* plane = x + (size_t)bc * HH * WW;

    // ---- A fragments: 15 coalesced dwordx4 loads, pinned resident ----
    const u32x4* ap = (const u32x4*)(aws + (cj * 4 + ci) * (AWS_CELL_BYTES / 4))
                      + cc * 4 + g;
    u32x4 af[KS];
    #pragma unroll
    for (int dy = 0; dy < KS; ++dy) af[dy] = ap[dy * 64];
    #pragma unroll
    for (int dy = 0; dy < KS; ++dy) asm volatile("" : "+v"(af[dy]));

    // ---- staging helpers (clamped-aligned float4 + edge broadcast selects) ----
    auto group_addr = [&](int idx) -> const float* {
        int row  = idx / 20;
        int c4   = idx - row * 20;
        int gy   = min(max(sy0 - PAD + row, celly0), celly1);
        int gx0  = bx0 - 8 + 4 * c4;
        int gx0c = min(max(gx0, cellx0), cellx0 + CELL - 4);
        return plane + (size_t)gy * WW + gx0c;
    };
    auto write_group = [&](int idx, float4 v) {
        int row = idx / 20;
        int c4  = idx - row * 20;
        int gx0 = bx0 - 8 + 4 * c4;
        bool lo = gx0 <  cellx0;
        bool hi = gx0 >  cellx0 + CELL - 4;
        float e0 = hi ? v.w : v.x;
        float e1 = lo ? v.x : (hi ? v.w : v.y);
        float e2 = lo ? v.x : (hi ? v.w : v.z);
        float e3 = lo ? v.x : v.w;
        f16x4 h;
        h[0] = (_Float16)e0; h[1] = (_Float16)e1;
        h[2] = (_Float16)e2; h[3] = (_Float16)e3;
        *(f16x4*)(s_tile + row * TCOLS + 4 * c4) = h;
    };
    auto issue_chunk = [&](int c, float4& v0, float4& v1, bool& h0, bool& h1) {
        int base = c * CGRP;
        int ng   = min(CGRP, NGRP - base);
        h0 = tid < ng;
        h1 = 256 + tid < ng;
        if (h0) v0 = *(const float4*)group_addr(base + tid);
        if (h1) v1 = *(const float4*)group_addr(base + 256 + tid);
    };
    auto write_chunk = [&](int c, float4 v0, float4 v1, bool h0, bool h1) {
        int base = c * CGRP;
        if (h0) write_group(base + tid, v0);
        if (h1) write_group(base + 256 + tid, v1);
    };

    // ---- prologue: chunks 0 and 1 (rows 0..31) ----
    {
        float4 a0, a1, b0, b1; bool ha0, ha1, hb0, hb1;
        issue_chunk(0, a0, a1, ha0, ha1);
        issue_chunk(1, b0, b1, hb0, hb1);
        write_chunk(0, a0, a1, ha0, ha1);
        write_chunk(1, b0, b1, hb0, hb1);
    }
    __syncthreads();

    // ---- pipelined main loop: 8 patches ----
    const _Float16* bbase = s_tile + cc * TCOLS + w * 16 + g * 8;
    float* oplane = out + (size_t)bc * HH * WW;

    #pragma unroll
    for (int jp = 0; jp < NJP; ++jp) {
        // issue next-next chunk's global loads (latency hides under MFMA below)
        const int c = jp + 2;
        float4 n0 = {0,0,0,0}, n1 = {0,0,0,0}; bool hn0 = false, hn1 = false;
        if (c < NCHUNK) issue_chunk(c, n0, n1, hn0, hn1);

        // compute patch jp (reads staged rows 16jp .. 16jp+30: chunks jp, jp+1)
        f32x4 acc0 = {0.f, 0.f, 0.f, 0.f};
        f32x4 acc1 = {0.f, 0.f, 0.f, 0.f};
        #pragma unroll
        for (int dy = 0; dy < KS; ++dy) {
            f16x8 b = *(const f16x8*)(bbase + (16 * jp + dy) * TCOLS);
            if (dy & 1)
                acc1 = __builtin_amdgcn_mfma_f32_16x16x32_f16(
                           __builtin_bit_cast(f16x8, af[dy]), b, acc1, 0, 0, 0);
            else
                acc0 = __builtin_amdgcn_mfma_f32_16x16x32_f16(
                           __builtin_bit_cast(f16x8, af[dy]), b, acc0, 0, 0, 0);
        }
        f32x4 r = acc0 + acc1;
        // D: col=lane&15 (image row), row=4*(lane>>4)+e (x position)
        float* op = oplane + (size_t)(sy0 + 16 * jp + cc) * WW + bx0 + 16 * w + 4 * g;
        *(f32x4*)op = r;

        // land the staged chunk (vmcnt drain) and publish to next iteration
        if (c < NCHUNK) write_chunk(c, n0, n1, hn0, hn1);
        __syncthreads();
    }
}

extern "C" void kernel_launch(void* const* d_in, const int* in_sizes, int n_in,
                              void* d_out, int out_size, void* d_ws, size_t ws_size,
                              hipStream_t stream) {
    (void)in_sizes; (void)n_in; (void)ws_size; (void)out_size;
    const float* x    = (const float*)d_in[0];
    const float* kern = (const float*)d_in[1];
    float* out        = (float*)d_out;
    unsigned int* aws = (unsigned int*)d_ws;   // 16 cells x 15 KiB = 240 KiB

    pb_prep_kernel<<<16, 256, 0, stream>>>(kern, aws);
    dim3 grid(WW / BX, 8, 8 * 3);   // 16 x-strips, 8 y-strips, 24 planes
    pb_mfma_kernel<<<grid, 256, 0, stream>>>(x, aws, out);
}